// Round 19
// baseline (341.751 us; speedup 1.0000x reference)
//
#include <hip/hip_runtime.h>
#include <math.h>

// MixingAttention forward: bf16/f16 MFMA GEMMs + f16 MFMA attention.
// B_=2048 windows, N=64, C=256, Ca=128, NH=8, HD=16, B=32 imgs, h=w=64.
// k46: fused qkv+attention+tail. PLAIN launch_bounds(256): allocator free
// to use ~150 VGPRs (no min-occupancy hint -> no scratch spills; cf. r10
// 33MB writes @ VGPR156 vs r11 104MB @ VGPR64).

#define BNR 0.9999950000374998f /* 1/sqrt(1+1e-5) */

typedef __attribute__((ext_vector_type(8))) short short8;
typedef __attribute__((ext_vector_type(4))) float f32x4;
typedef __attribute__((ext_vector_type(4))) _Float16 half4;
typedef __attribute__((ext_vector_type(8))) _Float16 half8;
typedef __attribute__((ext_vector_type(2))) _Float16 h2v;

__device__ __forceinline__ float gelu_f(float x) {
  const float z = x * (1.0f + 0.044715f * x * x);
  return x / (1.0f + __expf(-1.5957691216057308f * z));
}
__device__ __forceinline__ unsigned short f2bf(float f) {
  unsigned int u = __builtin_bit_cast(unsigned int, f);
  u += 0x7fffu + ((u >> 16) & 1u);
  return (unsigned short)(u >> 16);
}
__device__ __forceinline__ float bf2f(unsigned short h) {
  unsigned int u = ((unsigned int)h) << 16;
  return __builtin_bit_cast(float, u);
}
__device__ __forceinline__ void ld8(const unsigned short* p, float* o) {
  const short8 v = *(const short8*)p;
#pragma unroll
  for (int i = 0; i < 8; ++i) o[i] = bf2f((unsigned short)v[i]);
}
__device__ __forceinline__ unsigned int pkh(float a, float b) {
  return __builtin_bit_cast(unsigned int, __builtin_amdgcn_cvt_pkrtz(a, b));
}

// Swizzled LDS index for 64x256-ushort tile: 16B chunk ch XOR'd by row&7.
#define ATI(r, ch) (((r) << 8) + ((((ch) ^ ((r)&7))) << 3))

// ---------------------------------------------------------------- kpack
__global__ __launch_bounds__(256) void kpack(
    const float* __restrict__ aw, const float* __restrict__ qw,
    const float* __restrict__ prw, const float* __restrict__ ow,
    const float* __restrict__ sw1, const float* __restrict__ rpb,
    unsigned short* __restrict__ awp, unsigned short* __restrict__ qwp,
    unsigned short* __restrict__ prwp, unsigned short* __restrict__ owp,
    unsigned short* __restrict__ sw1p, unsigned short* __restrict__ bt) {
  const int b = blockIdx.x;
  if (b >= 356) {  // bias expansion: biasT[h][n][m] f16
    const int i = (b - 356) * 256 + threadIdx.x;  // 32768 total
    const int h = i >> 12, n = (i >> 6) & 63, m = i & 63;
    const int ny = n >> 3, nx = n & 7, my = m >> 3, mx = m & 7;
    const float v = rpb[((ny - my + 7) * 15 + (nx - mx + 7)) * 8 + h];
    bt[i] = __builtin_bit_cast(unsigned short, (_Float16)v);
    return;
  }
  const float* src; unsigned short* dst; int fs, K, N, NT, trans, f16o;
  if (b < 64)       { fs = b;       src = aw;  dst = awp;  K = 256; N = 128; NT = 8;  trans = 0; f16o = 0; }
  else if (b < 160) { fs = b - 64;  src = qw;  dst = qwp;  K = 128; N = 384; NT = 24; trans = 0; f16o = 0; }
  else if (b < 224) { fs = b - 160; src = prw; dst = prwp; K = 256; N = 128; NT = 8;  trans = 1; f16o = 1; }
  else if (b < 352) { fs = b - 224; src = ow;  dst = owp;  K = 256; N = 256; NT = 16; trans = 0; f16o = 0; }
  else              { fs = b - 352; src = sw1; dst = sw1p; K = 128; N = 16;  NT = 1;  trans = 1; f16o = 0; }
  const int ks = fs / NT, nt = fs % NT;
  for (int idx = threadIdx.x; idx < 512; idx += 256) {
    const int l = idx >> 3, i = idx & 7;
    const int k = ks * 32 + ((l >> 4) << 3) + i, n = nt * 16 + (l & 15);
    const float v = trans ? src[n * K + k] : src[k * N + n];
    dst[(fs * 64 + l) * 8 + i] =
        f16o ? __builtin_bit_cast(unsigned short, (_Float16)v) : f2bf(v);
  }
}

// ---------------------------------------------------------------- k1
__global__ __launch_bounds__(256) void k1_attn_ln(
    const float* __restrict__ x, const unsigned short* __restrict__ awp,
    const float* __restrict__ ab, const float* __restrict__ lg,
    const float* __restrict__ lb, unsigned short* __restrict__ xattn,
    unsigned short* __restrict__ xb) {
  const int tid = threadIdx.x, w = tid >> 6, l = tid & 63;
  const int lr = l & 15, lg4 = l >> 4;
  const int r0 = blockIdx.x * 64 + w * 16;
  const float* xp = x + (size_t)(r0 + lr) * 256 + lg4 * 8;
  unsigned short* xbp = xb + (size_t)(r0 + lr) * 256 + lg4 * 8;
  short8 a[8];
#pragma unroll
  for (int ks = 0; ks < 8; ++ks) {
    const float4 f0 = *(const float4*)(xp + ks * 32);
    const float4 f1 = *(const float4*)(xp + ks * 32 + 4);
    short8 av;
    av[0] = f2bf(f0.x); av[1] = f2bf(f0.y); av[2] = f2bf(f0.z); av[3] = f2bf(f0.w);
    av[4] = f2bf(f1.x); av[5] = f2bf(f1.y); av[6] = f2bf(f1.z); av[7] = f2bf(f1.w);
    a[ks] = av;
    uint4 hv;
    hv.x = pkh(f0.x, f0.y); hv.y = pkh(f0.z, f0.w);
    hv.z = pkh(f1.x, f1.y); hv.w = pkh(f1.z, f1.w);
    *(uint4*)(xbp + ks * 32) = hv;
  }
  f32x4 acc[8];
#pragma unroll
  for (int nt = 0; nt < 8; ++nt) acc[nt] = (f32x4)0.f;
#pragma unroll
  for (int nt = 0; nt < 8; ++nt)
#pragma unroll
    for (int ks = 0; ks < 8; ++ks) {
      const short8 bfr = *(const short8*)(awp + ((ks * 8 + nt) * 64 + l) * 8);
      acc[nt] = __builtin_amdgcn_mfma_f32_16x16x32_bf16(a[ks], bfr, acc[nt], 0, 0, 0);
    }
  float bias[8], gam[8], bet[8];
#pragma unroll
  for (int nt = 0; nt < 8; ++nt) {
    const int col = nt * 16 + lr;
    bias[nt] = ab[col]; gam[nt] = lg[col]; bet[nt] = lb[col];
  }
#pragma unroll
  for (int j = 0; j < 4; ++j) {
    float s = 0.f, qq = 0.f;
#pragma unroll
    for (int nt = 0; nt < 8; ++nt) {
      const float v = acc[nt][j] + bias[nt];
      acc[nt][j] = v; s += v; qq += v * v;
    }
    s += __shfl_xor(s, 1); s += __shfl_xor(s, 2);
    s += __shfl_xor(s, 4); s += __shfl_xor(s, 8);
    qq += __shfl_xor(qq, 1); qq += __shfl_xor(qq, 2);
    qq += __shfl_xor(qq, 4); qq += __shfl_xor(qq, 8);
    const float mean = s * (1.f / 128.f);
    const float var = qq * (1.f / 128.f) - mean * mean;
    const float rstd = rsqrtf(var + 1e-5f);
    const int row = r0 + lg4 * 4 + j;
#pragma unroll
    for (int nt = 0; nt < 8; ++nt)
      xattn[(size_t)row * 128 + nt * 16 + lr] =
          f2bf((acc[nt][j] - mean) * rstd * gam[nt] + bet[nt]);
  }
}

// ---------------------------------------------------------------- k25
__global__ __launch_bounds__(256) void k25_conv(
    const unsigned short* __restrict__ xb, const float* __restrict__ cw,
    const float* __restrict__ cb, const float* __restrict__ bg,
    const float* __restrict__ bb, const unsigned short* __restrict__ prwp,
    const float* __restrict__ prb, unsigned short* __restrict__ xpr,
    float* __restrict__ gpart) {
  __shared__ unsigned short gl[32][264];
  const int tid = threadIdx.x;
  const int bid = (blockIdx.x & 7) * 512 + (blockIdx.x >> 3);  // XCD swizzle
  const int b = bid >> 7;
  const int y = (bid >> 1) & 63;
  const int xt = (bid & 1) * 32;
  const int w = tid >> 6, l = tid & 63;
  {
    const int c0 = l << 2;
    h2v w01[9], w23[9];
#pragma unroll
    for (int k = 0; k < 9; ++k) {
      w01[k][0] = (_Float16)cw[(c0 + 0) * 9 + k];
      w01[k][1] = (_Float16)cw[(c0 + 1) * 9 + k];
      w23[k][0] = (_Float16)cw[(c0 + 2) * 9 + k];
      w23[k][1] = (_Float16)cw[(c0 + 3) * 9 + k];
    }
    const float4 cbf = *(const float4*)&cb[c0];
    float4 scf = *(const float4*)&bg[c0];
    scf.x *= BNR; scf.y *= BNR; scf.z *= BNR; scf.w *= BNR;
    const float4 sbf = *(const float4*)&bb[c0];
    h2v cb01 = {(_Float16)cbf.x, (_Float16)cbf.y};
    h2v cb23 = {(_Float16)cbf.z, (_Float16)cbf.w};
    h2v sc01 = {(_Float16)scf.x, (_Float16)scf.y};
    h2v sc23 = {(_Float16)scf.z, (_Float16)scf.w};
    h2v sb01 = {(_Float16)sbf.x, (_Float16)sbf.y};
    h2v sb23 = {(_Float16)sbf.z, (_Float16)sbf.w};
    float4 gsum = make_float4(0.f, 0.f, 0.f, 0.f);
    const int px0 = xt + w * 8;
#pragma unroll
    for (int sc2 = 0; sc2 < 2; ++sc2) {
      const int p0 = px0 + sc2 * 4;
      h2v v0[3][6], v1[3][6];
#pragma unroll
      for (int dy = 0; dy < 3; ++dy) {
        const int yy = y + dy - 1;
        const bool vy = (unsigned)yy < 64u;
        const int ybase = vy ? ((b * 64 + (yy >> 3) * 8) * 64 + (yy & 7) * 8) : 0;
#pragma unroll
        for (int q = 0; q < 6; ++q) {
          const int xx = p0 - 1 + q;
          h2v a = (h2v)(_Float16)0.f, c = (h2v)(_Float16)0.f;
          if (vy && (unsigned)xx < 64u) {
            const int row = ybase + (xx >> 3) * 64 + (xx & 7);
            const uint2 u = *(const uint2*)&xb[(size_t)row * 256 + c0];
            a = __builtin_bit_cast(h2v, u.x);
            c = __builtin_bit_cast(h2v, u.y);
          }
          v0[dy][q] = a; v1[dy][q] = c;
        }
      }
#pragma unroll
      for (int p = 0; p < 4; ++p) {
        h2v s0 = cb01, s1 = cb23;
#pragma unroll
        for (int dy = 0; dy < 3; ++dy)
#pragma unroll
          for (int dx = 0; dx < 3; ++dx) {
            s0 = w01[dy * 3 + dx] * v0[dy][p + dx] + s0;
            s1 = w23[dy * 3 + dx] * v1[dy][p + dx] + s1;
          }
        s0 = s0 * sc01 + sb01;
        s1 = s1 * sc23 + sb23;
        const float g0 = gelu_f((float)s0[0]), g1 = gelu_f((float)s0[1]);
        const float g2 = gelu_f((float)s1[0]), g3 = gelu_f((float)s1[1]);
        uint2 pk;
        pk.x = pkh(g0, g1); pk.y = pkh(g2, g3);
        *(uint2*)&gl[w * 8 + sc2 * 4 + p][c0] = pk;
        gsum.x += g0; gsum.y += g1; gsum.z += g2; gsum.w += g3;
      }
    }
    *(float4*)&gpart[(size_t)bid * 256 + c0] = gsum;
  }
  __syncthreads();
  const int lr = l & 15, lg4 = l >> 4;
  const int mr0 = (w & 1) * 16, nt0 = (w >> 1) * 4;
  half8 a[8];
#pragma unroll
  for (int ks = 0; ks < 8; ++ks)
    a[ks] = __builtin_bit_cast(half8,
                               *(const short8*)&gl[mr0 + lr][ks * 32 + lg4 * 8]);
  f32x4 acc[4];
#pragma unroll
  for (int nt = 0; nt < 4; ++nt) acc[nt] = (f32x4)0.f;
#pragma unroll
  for (int nt = 0; nt < 4; ++nt)
#pragma unroll
    for (int ks = 0; ks < 8; ++ks) {
      const half8 bfr = __builtin_bit_cast(
          half8, *(const short8*)(prwp + ((ks * 8 + nt0 + nt) * 64 + l) * 8));
      acc[nt] = __builtin_amdgcn_mfma_f32_16x16x32_f16(a[ks], bfr, acc[nt], 0, 0, 0);
    }
#pragma unroll
  for (int nt = 0; nt < 4; ++nt) {
    const int col = (nt0 + nt) * 16 + lr;
    const float bv = prb[col];
#pragma unroll
    for (int j = 0; j < 4; ++j) {
      const int pix = (b * 64 + y) * 64 + xt + mr0 + lg4 * 4 + j;
      xpr[(size_t)pix * 128 + col] = f2bf(acc[nt][j] + bv);
    }
  }
}

// ---------------------------------------------------------------- k3
__global__ __launch_bounds__(128) void k3_ci(
    const float* __restrict__ gp, const float* __restrict__ w1,
    const float* __restrict__ b1, const float* __restrict__ g1,
    const float* __restrict__ bb1, const float* __restrict__ w2,
    const float* __restrict__ b2, float* __restrict__ cis) {
  __shared__ float gm[256];
  __shared__ float c1[32];
  const int b = blockIdx.x, tid = threadIdx.x;
  for (int c = tid; c < 256; c += 128) {
    float s = 0.f;
    for (int p = 0; p < 128; ++p) s += gp[(size_t)(b * 128 + p) * 256 + c];
    gm[c] = s * (1.f / 4096.f);
  }
  __syncthreads();
  if (tid < 32) {
    float s = b1[tid];
    for (int c = 0; c < 256; ++c) s = fmaf(gm[c], w1[tid * 256 + c], s);
    s = s * (g1[tid] * BNR) + bb1[tid];
    c1[tid] = gelu_f(s);
  }
  __syncthreads();
  float s = b2[tid];
#pragma unroll
  for (int i = 0; i < 32; ++i) s = fmaf(c1[i], w2[tid * 32 + i], s);
  cis[b * 128 + tid] = 1.f / (1.f + __expf(-s));
}

// ---------------------------------------------------------------- k46
// Fused qkv+attention+tail, plain launch_bounds(256): no spill pressure.
__global__ __launch_bounds__(256) void k46_attn_tail(
    const unsigned short* __restrict__ xa, const unsigned short* __restrict__ qwp,
    const float* __restrict__ qb, const float* __restrict__ cis,
    const unsigned short* __restrict__ biasT, const unsigned short* __restrict__ xpr,
    const unsigned short* __restrict__ sw1p, const float* __restrict__ sb1,
    const float* __restrict__ sgc, const float* __restrict__ sbc,
    const float* __restrict__ sw2, const float* __restrict__ sb2,
    const float* __restrict__ cg, const float* __restrict__ cbb,
    const float* __restrict__ ag, const float* __restrict__ abb,
    const unsigned short* __restrict__ owp, const float* __restrict__ ob,
    float* __restrict__ out) {
  __shared__ __align__(16) unsigned char Ubuf[35840];  // QS|KS union; At overlay
  __shared__ float sifl[64];
  __shared__ float statl[64][2];
  __shared__ float pl[512];  // [ag | abb | cg*BNR | cbb]
  _Float16(*QS)[64][36] = reinterpret_cast<_Float16(*)[64][36]>(Ubuf);
  _Float16(*KS)[64][34] = reinterpret_cast<_Float16(*)[64][34]>(Ubuf + 18432);
  unsigned short* At = (unsigned short*)Ubuf;  // [64*256] (32KB)
  const int tid = threadIdx.x;
  const int win = blockIdx.x, img = win >> 6;
  const int w = tid >> 6, l = tid & 63, lr = l & 15, lg4 = l >> 4;
  const int wy = (win >> 3) & 7, wx = win & 7;
  // stage LN/gating params (consumed after barrier 2)
  for (int i = tid; i < 512; i += 256) {
    float v;
    if (i < 128) v = ag[i];
    else if (i < 256) v = abb[i - 128];
    else if (i < 384) v = cg[i - 256] * BNR;
    else v = cbb[i - 384];
    pl[i] = v;
  }
  // ---- pass A: Q (nt 2w,2w+1), K (nt 8+2w,8+2w+1) -> LDS transpose
  {
    float qbv[4];
#pragma unroll
    for (int t = 0; t < 4; ++t) {
      const int gnt = (t < 2) ? (2 * w + t) : (8 + 2 * w + t - 2);
      qbv[t] = qb[gnt * 16 + lr];
    }
    f32x4 acc[4][4];
#pragma unroll
    for (int mt = 0; mt < 4; ++mt)
#pragma unroll
      for (int t = 0; t < 4; ++t) acc[mt][t] = (f32x4)0.f;
#pragma unroll
    for (int ks = 0; ks < 4; ++ks) {
      short8 a[4];
#pragma unroll
      for (int mt = 0; mt < 4; ++mt)
        a[mt] = *(const short8*)(xa + (size_t)(win * 64 + mt * 16 + lr) * 128 +
                                 ks * 32 + lg4 * 8);
#pragma unroll
      for (int t = 0; t < 4; ++t) {
        const int gnt = (t < 2) ? (2 * w + t) : (8 + 2 * w + t - 2);
        const short8 bfr = *(const short8*)(qwp + ((ks * 24 + gnt) * 64 + l) * 8);
#pragma unroll
        for (int mt = 0; mt < 4; ++mt)
          acc[mt][t] = __builtin_amdgcn_mfma_f32_16x16x32_bf16(a[mt], bfr,
                                                               acc[mt][t], 0, 0, 0);
      }
    }
#pragma unroll
    for (int mt = 0; mt < 4; ++mt)
#pragma unroll
      for (int t = 0; t < 4; ++t)
#pragma unroll
        for (int j = 0; j < 4; ++j) {
          const int row = mt * 16 + lg4 * 4 + j;
          const float v = acc[mt][t][j] + qbv[t];
          if (t < 2) QS[w][row][t * 16 + lr] = (_Float16)(v * 0.25f);
          else KS[w][row][(t - 2) * 16 + lr] = (_Float16)v;
        }
  }
  // ---- pass B: V (nt 16+2w,16+2w+1) kept in regs as PV B-frags
  half4 bV2[2][4];
  {
    float qbv[2], cisv[2];
#pragma unroll
    for (int t = 0; t < 2; ++t) {
      qbv[t] = qb[(16 + 2 * w + t) * 16 + lr];
      cisv[t] = cis[img * 128 + (2 * w + t) * 16 + lr];
    }
    f32x4 accv[4][2];
#pragma unroll
    for (int mt = 0; mt < 4; ++mt)
#pragma unroll
      for (int t = 0; t < 2; ++t) accv[mt][t] = (f32x4)0.f;
#pragma unroll
    for (int ks = 0; ks < 4; ++ks) {
      short8 a[4];
#pragma unroll
      for (int mt = 0; mt < 4; ++mt)
        a[mt] = *(const short8*)(xa + (size_t)(win * 64 + mt * 16 + lr) * 128 +
                                 ks * 32 + lg4 * 8);
#pragma unroll
      for (int t = 0; t < 2; ++t) {
        const short8 bfr =
            *(const short8*)(qwp + ((ks * 24 + 16 + 2 * w + t) * 64 + l) * 8);
#pragma unroll
        for (int mt = 0; mt < 4; ++mt)
          accv[mt][t] = __builtin_amdgcn_mfma_f32_16x16x32_bf16(a[mt], bfr,
                                                                accv[mt][t], 0, 0, 0);
      }
    }
#pragma unroll
    for (int t = 0; t < 2; ++t)
#pragma unroll
      for (int kt = 0; kt < 4; ++kt) {
        half4 p;
#pragma unroll
        for (int i = 0; i < 4; ++i)
          p[i] = (_Float16)((accv[kt][t][i] + qbv[t]) * cisv[t]);
        bV2[t][kt] = p;
      }
  }
  // ---- attention per head, per-nt COLUMN (low register pressure)
  f32x4 o[2][4];
#pragma unroll
  for (int hi = 0; hi < 2; ++hi) {
    const int h = w * 2 + hi;
    half4 aK[4], bQ[4];
#pragma unroll
    for (int mt = 0; mt < 4; ++mt)
      aK[mt] = *(const half4*)&KS[w][mt * 16 + lr][hi * 16 + lg4 * 4];
#pragma unroll
    for (int nt = 0; nt < 4; ++nt)
      bQ[nt] = *(const half4*)&QS[w][nt * 16 + lr][hi * 16 + lg4 * 4];
#pragma unroll
    for (int nt = 0; nt < 4; ++nt) {
      f32x4 sc[4];
#pragma unroll
      for (int mt = 0; mt < 4; ++mt)
        sc[mt] = __builtin_amdgcn_mfma_f32_16x16x16f16(aK[mt], bQ[nt],
                                                       (f32x4)0.f, 0, 0, 0);
      const int n = nt * 16 + lr;
      const unsigned short* bp = biasT + (((h << 6) + n) << 6);
#pragma unroll
      for (int mt = 0; mt < 4; ++mt) {
        const half4 b4 = *(const half4*)(bp + mt * 16 + lg4 * 4);
        sc[mt][0] += (float)b4[0];
        sc[mt][1] += (float)b4[1];
        sc[mt][2] += (float)b4[2];
        sc[mt][3] += (float)b4[3];
      }
      float m0 = -1e30f;
#pragma unroll
      for (int mt = 0; mt < 4; ++mt)
#pragma unroll
        for (int r = 0; r < 4; ++r) m0 = fmaxf(m0, sc[mt][r]);
      m0 = fmaxf(m0, __shfl_xor(m0, 16));
      m0 = fmaxf(m0, __shfl_xor(m0, 32));
      float d0 = 0.f;
#pragma unroll
      for (int mt = 0; mt < 4; ++mt)
#pragma unroll
        for (int r = 0; r < 4; ++r) {
          const float e = __expf(sc[mt][r] - m0);
          sc[mt][r] = e;
          d0 += e;
        }
      d0 += __shfl_xor(d0, 16);
      d0 += __shfl_xor(d0, 32);
      const float inv = 1.f / d0;
      half4 pc[4];
#pragma unroll
      for (int kt = 0; kt < 4; ++kt) {
        half4 p;
#pragma unroll
        for (int r = 0; r < 4; ++r) p[r] = (_Float16)(sc[kt][r] * inv);
        pc[kt] = p;
      }
      o[hi][nt] = (f32x4)0.f;
#pragma unroll
      for (int kt = 0; kt < 4; ++kt)
        o[hi][nt] = __builtin_amdgcn_mfma_f32_16x16x16f16(pc[kt], bV2[hi][kt],
                                                          o[hi][nt], 0, 0, 0);
    }
  }
  // xpr prefetch (latency hides under the coming barrier wait)
  uint4 xr[4];
#pragma unroll
  for (int kk = 0; kk < 4; ++kk) {
    const int i = tid + kk * 256;
    const int r = i >> 4, c16 = i & 15;
    const int pix = (img * 64 + wy * 8 + (r >> 3)) * 64 + wx * 8 + (r & 7);
    xr[kk] = *(const uint4*)&xpr[(size_t)pix * 128 + c16 * 8];
  }
  __syncthreads();  // barrier 1: all waves done reading QS/KS -> At overlay
  // ---- write O (bf16) into At attn half; xpr regs into conv half
#pragma unroll
  for (int hi = 0; hi < 2; ++hi) {
    const int ch = w * 4 + hi * 2 + (lr >> 3), co = lr & 7;
#pragma unroll
    for (int nt = 0; nt < 4; ++nt)
#pragma unroll
      for (int r = 0; r < 4; ++r) {
        const int token = nt * 16 + lg4 * 4 + r;
        At[ATI(token, ch) + co] = f2bf(o[hi][nt][r]);
      }
  }
#pragma unroll
  for (int kk = 0; kk < 4; ++kk) {
    const int i = tid + kk * 256;
    const int r = i >> 4, c16 = i & 15;
    *(uint4*)&At[ATI(r, 16 + c16)] = xr[kk];
  }
  __syncthreads();  // barrier 2: At fully populated
  // ---- LN stats over attn half (rows of own wave band)
  {
    const int r = tid >> 2, q = tid & 3;
    float xv[32];
#pragma unroll
    for (int b8 = 0; b8 < 4; ++b8) ld8(&At[ATI(r, q * 4 + b8)], xv + b8 * 8);
    float ps = 0.f, pq = 0.f;
#pragma unroll
    for (int j = 0; j < 32; ++j) { ps += xv[j]; pq += xv[j] * xv[j]; }
    ps += __shfl_xor(ps, 1); ps += __shfl_xor(ps, 2);
    pq += __shfl_xor(pq, 1); pq += __shfl_xor(pq, 2);
    if (q == 0) {
      const float mean = ps * (1.f / 128.f);
      const float var = pq * (1.f / 128.f) - mean * mean;
      statl[r][0] = mean;
      statl[r][1] = rsqrtf(var + 1e-5f);
    }
  }
  // ---- si MLP via MFMA on raw attn half (own wave band)
  {
    const int row = w * 16 + lr;
    f32x4 sa = (f32x4)0.f;
#pragma unroll
    for (int ks = 0; ks < 4; ++ks) {
      const short8 a4 = *(const short8*)&At[ATI(row, ks * 4 + lg4)];
      const short8 bfr = *(const short8*)(sw1p + (ks * 64 + l) * 8);
      sa = __builtin_amdgcn_mfma_f32_16x16x32_bf16(a4, bfr, sa, 0, 0, 0);
    }
    const float sb1v = sb1[lr], g1v = sgc[lr] * BNR, b1v = sbc[lr];
    const float w2v = sw2[lr], sb2v = sb2[0];
#pragma unroll
    for (int j = 0; j < 4; ++j) {
      float s = (sa[j] + sb1v) * g1v + b1v;
      float p = gelu_f(s) * w2v;
      p += __shfl_xor(p, 1); p += __shfl_xor(p, 2);
      p += __shfl_xor(p, 4); p += __shfl_xor(p, 8);
      if (lr == 0) sifl[w * 16 + lg4 * 4 + j] = p + sb2v;
    }
  }
  // NO barrier: statl/sifl entries read below belong to this wave's band.
  // ---- final GEMM with in-register LN apply (attn) + gating (conv)
  const int row = w * 16 + lr;
  const float mean = statl[row][0], rstd = statl[row][1];
  const float sif = sifl[row];
  short8 af[8];
#pragma unroll
  for (int ks = 0; ks < 8; ++ks) {
    const short8 raw = *(const short8*)&At[ATI(row, ks * 4 + lg4)];
    const int cbase = (ks * 4 + lg4) * 8;  // global col of element 0
    short8 av;
    if (ks < 4) {
#pragma unroll
      for (int i = 0; i < 8; ++i) {
        const float v = bf2f((unsigned short)raw[i]);
        av[i] = f2bf((v - mean) * rstd * pl[cbase + i] + pl[128 + cbase + i]);
      }
    } else {
      const int cc = cbase - 128;
#pragma unroll
      for (int i = 0; i < 8; ++i) {
        const float v = bf2f((unsigned short)raw[i]);
        const float g = 1.f / (1.f + __expf(-sif * v));
        av[i] = f2bf(g * pl[256 + cc + i] + pl[384 + cc + i]);
      }
    }
    af[ks] = av;
  }
  f32x4 acc[16];
#pragma unroll
  for (int nt = 0; nt < 16; ++nt) acc[nt] = (f32x4)0.f;
#pragma unroll
  for (int nt = 0; nt < 16; ++nt)
#pragma unroll
    for (int ks = 0; ks < 8; ++ks) {
      const short8 bfr = *(const short8*)(owp + ((ks * 16 + nt) * 64 + l) * 8);
      acc[nt] = __builtin_amdgcn_mfma_f32_16x16x32_bf16(af[ks], bfr, acc[nt], 0, 0, 0);
    }
#pragma unroll
  for (int nt = 0; nt < 16; ++nt) {
    const int col = nt * 16 + lr;
    const float bv = ob[col];
#pragma unroll
    for (int j = 0; j < 4; ++j)
      __builtin_nontemporal_store(
          acc[nt][j] + bv,
          &out[(size_t)(win * 64 + w * 16 + lg4 * 4 + j) * 256 + col]);
  }
}

// ---------------------------------------------------------------- launch
extern "C" void kernel_launch(void* const* d_in, const int* in_sizes, int n_in,
                              void* d_out, int out_size, void* d_ws,
                              size_t ws_size, hipStream_t stream) {
  (void)in_sizes; (void)n_in; (void)out_size; (void)ws_size;
  const float* x      = (const float*)d_in[0];
  const float* rpb    = (const float*)d_in[1];
  const float* attn_w = (const float*)d_in[2];
  const float* attn_b = (const float*)d_in[3];
  const float* aln_g  = (const float*)d_in[4];
  const float* aln_b  = (const float*)d_in[5];
  const float* conv_w = (const float*)d_in[6];
  const float* conv_b = (const float*)d_in[7];
  const float* cbn_g  = (const float*)d_in[8];
  const float* cbn_b  = (const float*)d_in[9];
  const float* ci_w1  = (const float*)d_in[10];
  const float* ci_b1  = (const float*)d_in[11];
  const float* ci_bg  = (const float*)d_in[12];
  const float* ci_bb  = (const float*)d_in[13];
  const float* ci_w2  = (const float*)d_in[14];
  const float* ci_b2  = (const float*)d_in[15];
  const float* pr_w   = (const float*)d_in[16];
  const float* pr_b   = (const float*)d_in[17];
  const float* cn_g   = (const float*)d_in[18];
  const float* cn_b   = (const float*)d_in[19];
  const float* qkv_w  = (const float*)d_in[20];
  const float* qkv_b  = (const float*)d_in[21];
  const float* si_w1  = (const float*)d_in[22];
  const float* si_b1  = (const float*)d_in[23];
  const float* si_bg  = (const float*)d_in[24];
  const float* si_bb  = (const float*)d_in[25];
  const float* si_w2  = (const float*)d_in[26];
  const float* si_b2  = (const float*)d_in[27];
  const float* an_g   = (const float*)d_in[28];
  const float* an_b   = (const float*)d_in[29];
  const float* out_w  = (const float*)d_in[30];
  const float* out_b  = (const float*)d_in[31];

  unsigned short* xb    = (unsigned short*)d_ws;          // 33,554,432 e (f16)
  unsigned short* xattn = xb + 33554432;                  // 16,777,216 e
  unsigned short* xpr   = xattn + 16777216;               // 16,777,216 e
  float* gpart = (float*)(xpr + 16777216);                // 1,048,576 f
  float* cis   = gpart + 1048576;                         // 4,096 f
  unsigned short* awp   = (unsigned short*)(cis + 4096);  // 32,768 e
  unsigned short* qwp   = awp + 32768;                    // 49,152 e
  unsigned short* prwp  = qwp + 49152;                    // 32,768 e (f16)
  unsigned short* owp   = prwp + 32768;                   // 65,536 e
  unsigned short* sw1p  = owp + 65536;                    // 2,048 e
  unsigned short* biasT = sw1p + 2048;                    // 32,768 e (f16)

  kpack<<<484, 256, 0, stream>>>(attn_w, qkv_w, pr_w, out_w, si_w1, rpb,
                                 awp, qwp, prwp, owp, sw1p, biasT);
  k1_attn_ln<<<2048, 256, 0, stream>>>(x, awp, attn_b, aln_g, aln_b, xattn, xb);
  k25_conv<<<4096, 256, 0, stream>>>(xb, conv_w, conv_b, cbn_g, cbn_b, prwp,
                                     pr_b, xpr, gpart);
  k3_ci<<<32, 128, 0, stream>>>(gpart, ci_w1, ci_b1, ci_bg, ci_bb, ci_w2,
                                ci_b2, cis);
  k46_attn_tail<<<2048, 256, 0, stream>>>(
      xattn, qwp, qkv_b, cis, biasT, xpr, sw1p, si_b1, si_bg, si_bb, si_w2,
      si_b2, cn_g, cn_b, an_g, an_b, owp, out_b, (float*)d_out);
}

// Round 22
// 296.051 us; speedup vs baseline: 1.1544x; 1.1544x over previous
//
#include <hip/hip_runtime.h>
#include <math.h>

// MixingAttention forward: bf16/f16 MFMA GEMMs + f16 MFMA attention.
// B_=2048 windows, N=64, C=256, Ca=128, NH=8, HD=16, B=32 imgs, h=w=64.
// k46: fused qkv+attention+tail + LDS-staged full-line f32 stores.
// Obuf overlays own wave's dead At band (w*8192); an asm memory fence
// stops TBAA from hoisting float Obuf stores above ushort At reads.

#define BNR 0.9999950000374998f /* 1/sqrt(1+1e-5) */

typedef __attribute__((ext_vector_type(8))) short short8;
typedef __attribute__((ext_vector_type(4))) float f32x4;
typedef __attribute__((ext_vector_type(4))) _Float16 half4;
typedef __attribute__((ext_vector_type(8))) _Float16 half8;
typedef __attribute__((ext_vector_type(2))) _Float16 h2v;

__device__ __forceinline__ float gelu_f(float x) {
  const float z = x * (1.0f + 0.044715f * x * x);
  return x / (1.0f + __expf(-1.5957691216057308f * z));
}
__device__ __forceinline__ unsigned short f2bf(float f) {
  unsigned int u = __builtin_bit_cast(unsigned int, f);
  u += 0x7fffu + ((u >> 16) & 1u);
  return (unsigned short)(u >> 16);
}
__device__ __forceinline__ float bf2f(unsigned short h) {
  unsigned int u = ((unsigned int)h) << 16;
  return __builtin_bit_cast(float, u);
}
__device__ __forceinline__ void ld8(const unsigned short* p, float* o) {
  const short8 v = *(const short8*)p;
#pragma unroll
  for (int i = 0; i < 8; ++i) o[i] = bf2f((unsigned short)v[i]);
}
__device__ __forceinline__ unsigned int pkh(float a, float b) {
  return __builtin_bit_cast(unsigned int, __builtin_amdgcn_cvt_pkrtz(a, b));
}

// Swizzled LDS index for 64x256-ushort tile: 16B chunk ch XOR'd by row&7.
#define ATI(r, ch) (((r) << 8) + ((((ch) ^ ((r)&7))) << 3))

// ---------------------------------------------------------------- kpack
__global__ __launch_bounds__(256) void kpack(
    const float* __restrict__ aw, const float* __restrict__ qw,
    const float* __restrict__ prw, const float* __restrict__ ow,
    const float* __restrict__ sw1, const float* __restrict__ rpb,
    unsigned short* __restrict__ awp, unsigned short* __restrict__ qwp,
    unsigned short* __restrict__ prwp, unsigned short* __restrict__ owp,
    unsigned short* __restrict__ sw1p, unsigned short* __restrict__ bt) {
  const int b = blockIdx.x;
  if (b >= 356) {  // bias expansion: biasT[h][n][m] f16
    const int i = (b - 356) * 256 + threadIdx.x;  // 32768 total
    const int h = i >> 12, n = (i >> 6) & 63, m = i & 63;
    const int ny = n >> 3, nx = n & 7, my = m >> 3, mx = m & 7;
    const float v = rpb[((ny - my + 7) * 15 + (nx - mx + 7)) * 8 + h];
    bt[i] = __builtin_bit_cast(unsigned short, (_Float16)v);
    return;
  }
  const float* src; unsigned short* dst; int fs, K, N, NT, trans, f16o;
  if (b < 64)       { fs = b;       src = aw;  dst = awp;  K = 256; N = 128; NT = 8;  trans = 0; f16o = 0; }
  else if (b < 160) { fs = b - 64;  src = qw;  dst = qwp;  K = 128; N = 384; NT = 24; trans = 0; f16o = 0; }
  else if (b < 224) { fs = b - 160; src = prw; dst = prwp; K = 256; N = 128; NT = 8;  trans = 1; f16o = 1; }
  else if (b < 352) { fs = b - 224; src = ow;  dst = owp;  K = 256; N = 256; NT = 16; trans = 0; f16o = 0; }
  else              { fs = b - 352; src = sw1; dst = sw1p; K = 128; N = 16;  NT = 1;  trans = 1; f16o = 0; }
  const int ks = fs / NT, nt = fs % NT;
  for (int idx = threadIdx.x; idx < 512; idx += 256) {
    const int l = idx >> 3, i = idx & 7;
    const int k = ks * 32 + ((l >> 4) << 3) + i, n = nt * 16 + (l & 15);
    const float v = trans ? src[n * K + k] : src[k * N + n];
    dst[(fs * 64 + l) * 8 + i] =
        f16o ? __builtin_bit_cast(unsigned short, (_Float16)v) : f2bf(v);
  }
}

// ---------------------------------------------------------------- k1
__global__ __launch_bounds__(256) void k1_attn_ln(
    const float* __restrict__ x, const unsigned short* __restrict__ awp,
    const float* __restrict__ ab, const float* __restrict__ lg,
    const float* __restrict__ lb, unsigned short* __restrict__ xattn,
    unsigned short* __restrict__ xb) {
  const int tid = threadIdx.x, w = tid >> 6, l = tid & 63;
  const int lr = l & 15, lg4 = l >> 4;
  const int r0 = blockIdx.x * 64 + w * 16;
  const float* xp = x + (size_t)(r0 + lr) * 256 + lg4 * 8;
  unsigned short* xbp = xb + (size_t)(r0 + lr) * 256 + lg4 * 8;
  short8 a[8];
#pragma unroll
  for (int ks = 0; ks < 8; ++ks) {
    const float4 f0 = *(const float4*)(xp + ks * 32);
    const float4 f1 = *(const float4*)(xp + ks * 32 + 4);
    short8 av;
    av[0] = f2bf(f0.x); av[1] = f2bf(f0.y); av[2] = f2bf(f0.z); av[3] = f2bf(f0.w);
    av[4] = f2bf(f1.x); av[5] = f2bf(f1.y); av[6] = f2bf(f1.z); av[7] = f2bf(f1.w);
    a[ks] = av;
    uint4 hv;
    hv.x = pkh(f0.x, f0.y); hv.y = pkh(f0.z, f0.w);
    hv.z = pkh(f1.x, f1.y); hv.w = pkh(f1.z, f1.w);
    *(uint4*)(xbp + ks * 32) = hv;
  }
  f32x4 acc[8];
#pragma unroll
  for (int nt = 0; nt < 8; ++nt) acc[nt] = (f32x4)0.f;
#pragma unroll
  for (int nt = 0; nt < 8; ++nt)
#pragma unroll
    for (int ks = 0; ks < 8; ++ks) {
      const short8 bfr = *(const short8*)(awp + ((ks * 8 + nt) * 64 + l) * 8);
      acc[nt] = __builtin_amdgcn_mfma_f32_16x16x32_bf16(a[ks], bfr, acc[nt], 0, 0, 0);
    }
  float bias[8], gam[8], bet[8];
#pragma unroll
  for (int nt = 0; nt < 8; ++nt) {
    const int col = nt * 16 + lr;
    bias[nt] = ab[col]; gam[nt] = lg[col]; bet[nt] = lb[col];
  }
#pragma unroll
  for (int j = 0; j < 4; ++j) {
    float s = 0.f, qq = 0.f;
#pragma unroll
    for (int nt = 0; nt < 8; ++nt) {
      const float v = acc[nt][j] + bias[nt];
      acc[nt][j] = v; s += v; qq += v * v;
    }
    s += __shfl_xor(s, 1); s += __shfl_xor(s, 2);
    s += __shfl_xor(s, 4); s += __shfl_xor(s, 8);
    qq += __shfl_xor(qq, 1); qq += __shfl_xor(qq, 2);
    qq += __shfl_xor(qq, 4); qq += __shfl_xor(qq, 8);
    const float mean = s * (1.f / 128.f);
    const float var = qq * (1.f / 128.f) - mean * mean;
    const float rstd = rsqrtf(var + 1e-5f);
    const int row = r0 + lg4 * 4 + j;
#pragma unroll
    for (int nt = 0; nt < 8; ++nt)
      xattn[(size_t)row * 128 + nt * 16 + lr] =
          f2bf((acc[nt][j] - mean) * rstd * gam[nt] + bet[nt]);
  }
}

// ---------------------------------------------------------------- k25
__global__ __launch_bounds__(256) void k25_conv(
    const unsigned short* __restrict__ xb, const float* __restrict__ cw,
    const float* __restrict__ cb, const float* __restrict__ bg,
    const float* __restrict__ bb, const unsigned short* __restrict__ prwp,
    const float* __restrict__ prb, unsigned short* __restrict__ xpr,
    float* __restrict__ gpart) {
  __shared__ unsigned short gl[32][264];
  const int tid = threadIdx.x;
  const int bid = (blockIdx.x & 7) * 512 + (blockIdx.x >> 3);  // XCD swizzle
  const int b = bid >> 7;
  const int y = (bid >> 1) & 63;
  const int xt = (bid & 1) * 32;
  const int w = tid >> 6, l = tid & 63;
  {
    const int c0 = l << 2;
    h2v w01[9], w23[9];
#pragma unroll
    for (int k = 0; k < 9; ++k) {
      w01[k][0] = (_Float16)cw[(c0 + 0) * 9 + k];
      w01[k][1] = (_Float16)cw[(c0 + 1) * 9 + k];
      w23[k][0] = (_Float16)cw[(c0 + 2) * 9 + k];
      w23[k][1] = (_Float16)cw[(c0 + 3) * 9 + k];
    }
    const float4 cbf = *(const float4*)&cb[c0];
    float4 scf = *(const float4*)&bg[c0];
    scf.x *= BNR; scf.y *= BNR; scf.z *= BNR; scf.w *= BNR;
    const float4 sbf = *(const float4*)&bb[c0];
    h2v cb01 = {(_Float16)cbf.x, (_Float16)cbf.y};
    h2v cb23 = {(_Float16)cbf.z, (_Float16)cbf.w};
    h2v sc01 = {(_Float16)scf.x, (_Float16)scf.y};
    h2v sc23 = {(_Float16)scf.z, (_Float16)scf.w};
    h2v sb01 = {(_Float16)sbf.x, (_Float16)sbf.y};
    h2v sb23 = {(_Float16)sbf.z, (_Float16)sbf.w};
    float4 gsum = make_float4(0.f, 0.f, 0.f, 0.f);
    const int px0 = xt + w * 8;
#pragma unroll
    for (int sc2 = 0; sc2 < 2; ++sc2) {
      const int p0 = px0 + sc2 * 4;
      h2v v0[3][6], v1[3][6];
#pragma unroll
      for (int dy = 0; dy < 3; ++dy) {
        const int yy = y + dy - 1;
        const bool vy = (unsigned)yy < 64u;
        const int ybase = vy ? ((b * 64 + (yy >> 3) * 8) * 64 + (yy & 7) * 8) : 0;
#pragma unroll
        for (int q = 0; q < 6; ++q) {
          const int xx = p0 - 1 + q;
          h2v a = (h2v)(_Float16)0.f, c = (h2v)(_Float16)0.f;
          if (vy && (unsigned)xx < 64u) {
            const int row = ybase + (xx >> 3) * 64 + (xx & 7);
            const uint2 u = *(const uint2*)&xb[(size_t)row * 256 + c0];
            a = __builtin_bit_cast(h2v, u.x);
            c = __builtin_bit_cast(h2v, u.y);
          }
          v0[dy][q] = a; v1[dy][q] = c;
        }
      }
#pragma unroll
      for (int p = 0; p < 4; ++p) {
        h2v s0 = cb01, s1 = cb23;
#pragma unroll
        for (int dy = 0; dy < 3; ++dy)
#pragma unroll
          for (int dx = 0; dx < 3; ++dx) {
            s0 = w01[dy * 3 + dx] * v0[dy][p + dx] + s0;
            s1 = w23[dy * 3 + dx] * v1[dy][p + dx] + s1;
          }
        s0 = s0 * sc01 + sb01;
        s1 = s1 * sc23 + sb23;
        const float g0 = gelu_f((float)s0[0]), g1 = gelu_f((float)s0[1]);
        const float g2 = gelu_f((float)s1[0]), g3 = gelu_f((float)s1[1]);
        uint2 pk;
        pk.x = pkh(g0, g1); pk.y = pkh(g2, g3);
        *(uint2*)&gl[w * 8 + sc2 * 4 + p][c0] = pk;
        gsum.x += g0; gsum.y += g1; gsum.z += g2; gsum.w += g3;
      }
    }
    *(float4*)&gpart[(size_t)bid * 256 + c0] = gsum;
  }
  __syncthreads();
  const int lr = l & 15, lg4 = l >> 4;
  const int mr0 = (w & 1) * 16, nt0 = (w >> 1) * 4;
  half8 a[8];
#pragma unroll
  for (int ks = 0; ks < 8; ++ks)
    a[ks] = __builtin_bit_cast(half8,
                               *(const short8*)&gl[mr0 + lr][ks * 32 + lg4 * 8]);
  f32x4 acc[4];
#pragma unroll
  for (int nt = 0; nt < 4; ++nt) acc[nt] = (f32x4)0.f;
#pragma unroll
  for (int nt = 0; nt < 4; ++nt)
#pragma unroll
    for (int ks = 0; ks < 8; ++ks) {
      const half8 bfr = __builtin_bit_cast(
          half8, *(const short8*)(prwp + ((ks * 8 + nt0 + nt) * 64 + l) * 8));
      acc[nt] = __builtin_amdgcn_mfma_f32_16x16x32_f16(a[ks], bfr, acc[nt], 0, 0, 0);
    }
#pragma unroll
  for (int nt = 0; nt < 4; ++nt) {
    const int col = (nt0 + nt) * 16 + lr;
    const float bv = prb[col];
#pragma unroll
    for (int j = 0; j < 4; ++j) {
      const int pix = (b * 64 + y) * 64 + xt + mr0 + lg4 * 4 + j;
      xpr[(size_t)pix * 128 + col] = f2bf(acc[nt][j] + bv);
    }
  }
}

// ---------------------------------------------------------------- k3
__global__ __launch_bounds__(128) void k3_ci(
    const float* __restrict__ gp, const float* __restrict__ w1,
    const float* __restrict__ b1, const float* __restrict__ g1,
    const float* __restrict__ bb1, const float* __restrict__ w2,
    const float* __restrict__ b2, float* __restrict__ cis) {
  __shared__ float gm[256];
  __shared__ float c1[32];
  const int b = blockIdx.x, tid = threadIdx.x;
  for (int c = tid; c < 256; c += 128) {
    float s = 0.f;
    for (int p = 0; p < 128; ++p) s += gp[(size_t)(b * 128 + p) * 256 + c];
    gm[c] = s * (1.f / 4096.f);
  }
  __syncthreads();
  if (tid < 32) {
    float s = b1[tid];
    for (int c = 0; c < 256; ++c) s = fmaf(gm[c], w1[tid * 256 + c], s);
    s = s * (g1[tid] * BNR) + bb1[tid];
    c1[tid] = gelu_f(s);
  }
  __syncthreads();
  float s = b2[tid];
#pragma unroll
  for (int i = 0; i < 32; ++i) s = fmaf(c1[i], w2[tid * 32 + i], s);
  cis[b * 128 + tid] = 1.f / (1.f + __expf(-s));
}

// ---------------------------------------------------------------- k46
// Fused qkv+attention+tail, bounds(256,4); LDS-staged full-line out stores
// through each wave's OWN dead At band (Ubuf + w*8192), with a compiler
// memory fence preventing TBAA reordering of float stores vs ushort loads.
__global__ __launch_bounds__(256, 4) void k46_attn_tail(
    const unsigned short* __restrict__ xa, const unsigned short* __restrict__ qwp,
    const float* __restrict__ qb, const float* __restrict__ cis,
    const unsigned short* __restrict__ biasT, const unsigned short* __restrict__ xpr,
    const unsigned short* __restrict__ sw1p, const float* __restrict__ sb1,
    const float* __restrict__ sgc, const float* __restrict__ sbc,
    const float* __restrict__ sw2, const float* __restrict__ sb2,
    const float* __restrict__ cg, const float* __restrict__ cbb,
    const float* __restrict__ ag, const float* __restrict__ abb,
    const unsigned short* __restrict__ owp, const float* __restrict__ ob,
    float* __restrict__ out) {
  __shared__ __align__(16) unsigned char Ubuf[35840];  // QS|KS union; At overlay
  __shared__ float sifl[64];
  __shared__ float statl[64][2];
  __shared__ float pl[512];  // [ag | abb | cg*BNR | cbb]
  _Float16(*QS)[64][36] = reinterpret_cast<_Float16(*)[64][36]>(Ubuf);
  _Float16(*KS)[64][34] = reinterpret_cast<_Float16(*)[64][34]>(Ubuf + 18432);
  unsigned short* At = (unsigned short*)Ubuf;  // [64*256] (32KB)
  const int tid = threadIdx.x;
  const int win = blockIdx.x, img = win >> 6;
  const int w = tid >> 6, l = tid & 63, lr = l & 15, lg4 = l >> 4;
  const int wy = (win >> 3) & 7, wx = win & 7;
  // stage LN/gating params (consumed after barrier 2)
  for (int i = tid; i < 512; i += 256) {
    float v;
    if (i < 128) v = ag[i];
    else if (i < 256) v = abb[i - 128];
    else if (i < 384) v = cg[i - 256] * BNR;
    else v = cbb[i - 384];
    pl[i] = v;
  }
  // ---- pass A: Q (nt 2w,2w+1), K (nt 8+2w,8+2w+1) -> LDS transpose
  {
    float qbv[4];
#pragma unroll
    for (int t = 0; t < 4; ++t) {
      const int gnt = (t < 2) ? (2 * w + t) : (8 + 2 * w + t - 2);
      qbv[t] = qb[gnt * 16 + lr];
    }
    f32x4 acc[4][4];
#pragma unroll
    for (int mt = 0; mt < 4; ++mt)
#pragma unroll
      for (int t = 0; t < 4; ++t) acc[mt][t] = (f32x4)0.f;
#pragma unroll
    for (int ks = 0; ks < 4; ++ks) {
      short8 a[4];
#pragma unroll
      for (int mt = 0; mt < 4; ++mt)
        a[mt] = *(const short8*)(xa + (size_t)(win * 64 + mt * 16 + lr) * 128 +
                                 ks * 32 + lg4 * 8);
#pragma unroll
      for (int t = 0; t < 4; ++t) {
        const int gnt = (t < 2) ? (2 * w + t) : (8 + 2 * w + t - 2);
        const short8 bfr = *(const short8*)(qwp + ((ks * 24 + gnt) * 64 + l) * 8);
#pragma unroll
        for (int mt = 0; mt < 4; ++mt)
          acc[mt][t] = __builtin_amdgcn_mfma_f32_16x16x32_bf16(a[mt], bfr,
                                                               acc[mt][t], 0, 0, 0);
      }
    }
#pragma unroll
    for (int mt = 0; mt < 4; ++mt)
#pragma unroll
      for (int t = 0; t < 4; ++t)
#pragma unroll
        for (int j = 0; j < 4; ++j) {
          const int row = mt * 16 + lg4 * 4 + j;
          const float v = acc[mt][t][j] + qbv[t];
          if (t < 2) QS[w][row][t * 16 + lr] = (_Float16)(v * 0.25f);
          else KS[w][row][(t - 2) * 16 + lr] = (_Float16)v;
        }
  }
  // ---- pass B: V (nt 16+2w,16+2w+1) kept in regs as PV B-frags
  half4 bV2[2][4];
  {
    float qbv[2], cisv[2];
#pragma unroll
    for (int t = 0; t < 2; ++t) {
      qbv[t] = qb[(16 + 2 * w + t) * 16 + lr];
      cisv[t] = cis[img * 128 + (2 * w + t) * 16 + lr];
    }
    f32x4 accv[4][2];
#pragma unroll
    for (int mt = 0; mt < 4; ++mt)
#pragma unroll
      for (int t = 0; t < 2; ++t) accv[mt][t] = (f32x4)0.f;
#pragma unroll
    for (int ks = 0; ks < 4; ++ks) {
      short8 a[4];
#pragma unroll
      for (int mt = 0; mt < 4; ++mt)
        a[mt] = *(const short8*)(xa + (size_t)(win * 64 + mt * 16 + lr) * 128 +
                                 ks * 32 + lg4 * 8);
#pragma unroll
      for (int t = 0; t < 2; ++t) {
        const short8 bfr =
            *(const short8*)(qwp + ((ks * 24 + 16 + 2 * w + t) * 64 + l) * 8);
#pragma unroll
        for (int mt = 0; mt < 4; ++mt)
          accv[mt][t] = __builtin_amdgcn_mfma_f32_16x16x32_bf16(a[mt], bfr,
                                                                accv[mt][t], 0, 0, 0);
      }
    }
#pragma unroll
    for (int t = 0; t < 2; ++t)
#pragma unroll
      for (int kt = 0; kt < 4; ++kt) {
        half4 p;
#pragma unroll
        for (int i = 0; i < 4; ++i)
          p[i] = (_Float16)((accv[kt][t][i] + qbv[t]) * cisv[t]);
        bV2[t][kt] = p;
      }
  }
  // ---- attention per head, per-nt COLUMN (low register pressure)
  f32x4 o[2][4];
#pragma unroll
  for (int hi = 0; hi < 2; ++hi) {
    const int h = w * 2 + hi;
    half4 aK[4], bQ[4];
#pragma unroll
    for (int mt = 0; mt < 4; ++mt)
      aK[mt] = *(const half4*)&KS[w][mt * 16 + lr][hi * 16 + lg4 * 4];
#pragma unroll
    for (int nt = 0; nt < 4; ++nt)
      bQ[nt] = *(const half4*)&QS[w][nt * 16 + lr][hi * 16 + lg4 * 4];
#pragma unroll
    for (int nt = 0; nt < 4; ++nt) {
      f32x4 sc[4];
#pragma unroll
      for (int mt = 0; mt < 4; ++mt)
        sc[mt] = __builtin_amdgcn_mfma_f32_16x16x16f16(aK[mt], bQ[nt],
                                                       (f32x4)0.f, 0, 0, 0);
      const int n = nt * 16 + lr;
      const unsigned short* bp = biasT + (((h << 6) + n) << 6);
#pragma unroll
      for (int mt = 0; mt < 4; ++mt) {
        const half4 b4 = *(const half4*)(bp + mt * 16 + lg4 * 4);
        sc[mt][0] += (float)b4[0];
        sc[mt][1] += (float)b4[1];
        sc[mt][2] += (float)b4[2];
        sc[mt][3] += (float)b4[3];
      }
      float m0 = -1e30f;
#pragma unroll
      for (int mt = 0; mt < 4; ++mt)
#pragma unroll
        for (int r = 0; r < 4; ++r) m0 = fmaxf(m0, sc[mt][r]);
      m0 = fmaxf(m0, __shfl_xor(m0, 16));
      m0 = fmaxf(m0, __shfl_xor(m0, 32));
      float d0 = 0.f;
#pragma unroll
      for (int mt = 0; mt < 4; ++mt)
#pragma unroll
        for (int r = 0; r < 4; ++r) {
          const float e = __expf(sc[mt][r] - m0);
          sc[mt][r] = e;
          d0 += e;
        }
      d0 += __shfl_xor(d0, 16);
      d0 += __shfl_xor(d0, 32);
      const float inv = 1.f / d0;
      half4 pc[4];
#pragma unroll
      for (int kt = 0; kt < 4; ++kt) {
        half4 p;
#pragma unroll
        for (int r = 0; r < 4; ++r) p[r] = (_Float16)(sc[kt][r] * inv);
        pc[kt] = p;
      }
      o[hi][nt] = (f32x4)0.f;
#pragma unroll
      for (int kt = 0; kt < 4; ++kt)
        o[hi][nt] = __builtin_amdgcn_mfma_f32_16x16x16f16(pc[kt], bV2[hi][kt],
                                                          o[hi][nt], 0, 0, 0);
    }
  }
  // xpr prefetch (latency hides under the coming barrier wait)
  uint4 xr[4];
#pragma unroll
  for (int kk = 0; kk < 4; ++kk) {
    const int i = tid + kk * 256;
    const int r = i >> 4, c16 = i & 15;
    const int pix = (img * 64 + wy * 8 + (r >> 3)) * 64 + wx * 8 + (r & 7);
    xr[kk] = *(const uint4*)&xpr[(size_t)pix * 128 + c16 * 8];
  }
  __syncthreads();  // barrier 1: all waves done reading QS/KS -> At overlay
  // ---- write O (bf16) into At attn half; xpr regs into conv half
#pragma unroll
  for (int hi = 0; hi < 2; ++hi) {
    const int ch = w * 4 + hi * 2 + (lr >> 3), co = lr & 7;
#pragma unroll
    for (int nt = 0; nt < 4; ++nt)
#pragma unroll
      for (int r = 0; r < 4; ++r) {
        const int token = nt * 16 + lg4 * 4 + r;
        At[ATI(token, ch) + co] = f2bf(o[hi][nt][r]);
      }
  }
#pragma unroll
  for (int kk = 0; kk < 4; ++kk) {
    const int i = tid + kk * 256;
    const int r = i >> 4, c16 = i & 15;
    *(uint4*)&At[ATI(r, 16 + c16)] = xr[kk];
  }
  __syncthreads();  // barrier 2: At fully populated
  // ---- LN stats over attn half (rows of own wave band)
  {
    const int r = tid >> 2, q = tid & 3;
    float xv[32];
#pragma unroll
    for (int b8 = 0; b8 < 4; ++b8) ld8(&At[ATI(r, q * 4 + b8)], xv + b8 * 8);
    float ps = 0.f, pq = 0.f;
#pragma unroll
    for (int j = 0; j < 32; ++j) { ps += xv[j]; pq += xv[j] * xv[j]; }
    ps += __shfl_xor(ps, 1); ps += __shfl_xor(ps, 2);
    pq += __shfl_xor(pq, 1); pq += __shfl_xor(pq, 2);
    if (q == 0) {
      const float mean = ps * (1.f / 128.f);
      const float var = pq * (1.f / 128.f) - mean * mean;
      statl[r][0] = mean;
      statl[r][1] = rsqrtf(var + 1e-5f);
    }
  }
  // ---- si MLP via MFMA on raw attn half (own wave band)
  {
    const int row = w * 16 + lr;
    f32x4 sa = (f32x4)0.f;
#pragma unroll
    for (int ks = 0; ks < 4; ++ks) {
      const short8 a4 = *(const short8*)&At[ATI(row, ks * 4 + lg4)];
      const short8 bfr = *(const short8*)(sw1p + (ks * 64 + l) * 8);
      sa = __builtin_amdgcn_mfma_f32_16x16x32_bf16(a4, bfr, sa, 0, 0, 0);
    }
    const float sb1v = sb1[lr], g1v = sgc[lr] * BNR, b1v = sbc[lr];
    const float w2v = sw2[lr], sb2v = sb2[0];
#pragma unroll
    for (int j = 0; j < 4; ++j) {
      float s = (sa[j] + sb1v) * g1v + b1v;
      float p = gelu_f(s) * w2v;
      p += __shfl_xor(p, 1); p += __shfl_xor(p, 2);
      p += __shfl_xor(p, 4); p += __shfl_xor(p, 8);
      if (lr == 0) sifl[w * 16 + lg4 * 4 + j] = p + sb2v;
    }
  }
  // NO barrier: statl/sifl entries read below belong to this wave's band.
  // ---- final GEMM with in-register LN apply (attn) + gating (conv)
  const int row = w * 16 + lr;
  const float mean = statl[row][0], rstd = statl[row][1];
  const float sif = sifl[row];
  short8 af[8];
#pragma unroll
  for (int ks = 0; ks < 8; ++ks) {
    const short8 raw = *(const short8*)&At[ATI(row, ks * 4 + lg4)];
    const int cbase = (ks * 4 + lg4) * 8;  // global col of element 0
    short8 av;
    if (ks < 4) {
#pragma unroll
      for (int i = 0; i < 8; ++i) {
        const float v = bf2f((unsigned short)raw[i]);
        av[i] = f2bf((v - mean) * rstd * pl[cbase + i] + pl[128 + cbase + i]);
      }
    } else {
      const int cc = cbase - 128;
#pragma unroll
      for (int i = 0; i < 8; ++i) {
        const float v = bf2f((unsigned short)raw[i]);
        const float g = 1.f / (1.f + __expf(-sif * v));
        av[i] = f2bf(g * pl[256 + cc + i] + pl[384 + cc + i]);
      }
    }
    af[ks] = av;
  }
  // Compiler memory fence: all At (ushort) reads above MUST be ordered
  // before the float Obuf stores below (TBAA would otherwise allow
  // hoisting the stores, clobbering At before the af loads).
  asm volatile("" ::: "memory");
  f32x4 acc[16];
#pragma unroll
  for (int nt = 0; nt < 16; ++nt) acc[nt] = (f32x4)0.f;
#pragma unroll
  for (int nt = 0; nt < 16; ++nt)
#pragma unroll
    for (int ks = 0; ks < 8; ++ks) {
      const short8 bfr = *(const short8*)(owp + ((ks * 16 + nt) * 64 + l) * 8);
      acc[nt] = __builtin_amdgcn_mfma_f32_16x16x32_bf16(af[ks], bfr, acc[nt], 0, 0, 0);
    }
  // ---- LDS-staged FULL-LINE stores through OWN dead At band (w*8192).
  float* Obuf = (float*)(Ubuf + w * 8192);  // 8 rows x 256 f = 8KB, 2 passes
#pragma unroll
  for (int p = 0; p < 2; ++p) {
    if ((lg4 >> 1) == p) {
      const int rb = (lg4 & 1) * 4;  // local rows rb..rb+3
#pragma unroll
      for (int nt = 0; nt < 16; ++nt) {
        const float bv = ob[nt * 16 + lr];
#pragma unroll
        for (int j = 0; j < 4; ++j)
          Obuf[(rb + j) * 256 + nt * 16 + lr] = acc[nt][j] + bv;
      }
    }
    asm volatile("" ::: "memory");
#pragma unroll
    for (int it = 0; it < 8; ++it) {
      const float4 v = *(const float4*)&Obuf[it * 256 + l * 4];
      *(float4*)&out[(size_t)(win * 64 + w * 16 + p * 8 + it) * 256 + l * 4] = v;
    }
    asm volatile("" ::: "memory");
  }
}

// ---------------------------------------------------------------- launch
extern "C" void kernel_launch(void* const* d_in, const int* in_sizes, int n_in,
                              void* d_out, int out_size, void* d_ws,
                              size_t ws_size, hipStream_t stream) {
  (void)in_sizes; (void)n_in; (void)out_size; (void)ws_size;
  const float* x      = (const float*)d_in[0];
  const float* rpb    = (const float*)d_in[1];
  const float* attn_w = (const float*)d_in[2];
  const float* attn_b = (const float*)d_in[3];
  const float* aln_g  = (const float*)d_in[4];
  const float* aln_b  = (const float*)d_in[5];
  const float* conv_w = (const float*)d_in[6];
  const float* conv_b = (const float*)d_in[7];
  const float* cbn_g  = (const float*)d_in[8];
  const float* cbn_b  = (const float*)d_in[9];
  const float* ci_w1  = (const float*)d_in[10];
  const float* ci_b1  = (const float*)d_in[11];
  const float* ci_bg  = (const float*)d_in[12];
  const float* ci_bb  = (const float*)d_in[13];
  const float* ci_w2  = (const float*)d_in[14];
  const float* ci_b2  = (const float*)d_in[15];
  const float* pr_w   = (const float*)d_in[16];
  const float* pr_b   = (const float*)d_in[17];
  const float* cn_g   = (const float*)d_in[18];
  const float* cn_b   = (const float*)d_in[19];
  const float* qkv_w  = (const float*)d_in[20];
  const float* qkv_b  = (const float*)d_in[21];
  const float* si_w1  = (const float*)d_in[22];
  const float* si_b1  = (const float*)d_in[23];
  const float* si_bg  = (const float*)d_in[24];
  const float* si_bb  = (const float*)d_in[25];
  const float* si_w2  = (const float*)d_in[26];
  const float* si_b2  = (const float*)d_in[27];
  const float* an_g   = (const float*)d_in[28];
  const float* an_b   = (const float*)d_in[29];
  const float* out_w  = (const float*)d_in[30];
  const float* out_b  = (const float*)d_in[31];

  unsigned short* xb    = (unsigned short*)d_ws;          // 33,554,432 e (f16)
  unsigned short* xattn = xb + 33554432;                  // 16,777,216 e
  unsigned short* xpr   = xattn + 16777216;               // 16,777,216 e
  float* gpart = (float*)(xpr + 16777216);                // 1,048,576 f
  float* cis   = gpart + 1048576;                         // 4,096 f
  unsigned short* awp   = (unsigned short*)(cis + 4096);  // 32,768 e
  unsigned short* qwp   = awp + 32768;                    // 49,152 e
  unsigned short* prwp  = qwp + 49152;                    // 32,768 e (f16)
  unsigned short* owp   = prwp + 32768;                   // 65,536 e
  unsigned short* sw1p  = owp + 65536;                    // 2,048 e
  unsigned short* biasT = sw1p + 2048;                    // 32,768 e (f16)

  kpack<<<484, 256, 0, stream>>>(attn_w, qkv_w, pr_w, out_w, si_w1, rpb,
                                 awp, qwp, prwp, owp, sw1p, biasT);
  k1_attn_ln<<<2048, 256, 0, stream>>>(x, awp, attn_b, aln_g, aln_b, xattn, xb);
  k25_conv<<<4096, 256, 0, stream>>>(xb, conv_w, conv_b, cbn_g, cbn_b, prwp,
                                     pr_b, xpr, gpart);
  k3_ci<<<32, 128, 0, stream>>>(gpart, ci_w1, ci_b1, ci_bg, ci_bb, ci_w2,
                                ci_b2, cis);
  k46_attn_tail<<<2048, 256, 0, stream>>>(
      xattn, qwp, qkv_b, cis, biasT, xpr, sw1p, si_b1, si_bg, si_bb, si_w2,
      si_b2, cn_g, cn_b, an_g, an_b, owp, out_b, (float*)d_out);
}

// Round 23
// 267.203 us; speedup vs baseline: 1.2790x; 1.1080x over previous
//
#include <hip/hip_runtime.h>
#include <math.h>

// MixingAttention forward: bf16/f16 MFMA GEMMs + f16 MFMA attention.
// B_=2048 windows, N=64, C=256, Ca=128, NH=8, HD=16, B=32 imgs, h=w=64.
// k46: fused qkv+attention+tail. Tail restructured: only 2 barriers (all
// post-At consumers are wave-local); LN+gating folded into final-GEMM
// fragment loads; nontemporal out stores.  [r18 best config, locked in]

#define BNR 0.9999950000374998f /* 1/sqrt(1+1e-5) */

typedef __attribute__((ext_vector_type(8))) short short8;
typedef __attribute__((ext_vector_type(4))) float f32x4;
typedef __attribute__((ext_vector_type(4))) _Float16 half4;
typedef __attribute__((ext_vector_type(8))) _Float16 half8;
typedef __attribute__((ext_vector_type(2))) _Float16 h2v;

__device__ __forceinline__ float gelu_f(float x) {
  const float z = x * (1.0f + 0.044715f * x * x);
  return x / (1.0f + __expf(-1.5957691216057308f * z));
}
__device__ __forceinline__ unsigned short f2bf(float f) {
  unsigned int u = __builtin_bit_cast(unsigned int, f);
  u += 0x7fffu + ((u >> 16) & 1u);
  return (unsigned short)(u >> 16);
}
__device__ __forceinline__ float bf2f(unsigned short h) {
  unsigned int u = ((unsigned int)h) << 16;
  return __builtin_bit_cast(float, u);
}
__device__ __forceinline__ void ld8(const unsigned short* p, float* o) {
  const short8 v = *(const short8*)p;
#pragma unroll
  for (int i = 0; i < 8; ++i) o[i] = bf2f((unsigned short)v[i]);
}
__device__ __forceinline__ unsigned int pkh(float a, float b) {
  return __builtin_bit_cast(unsigned int, __builtin_amdgcn_cvt_pkrtz(a, b));
}

// Swizzled LDS index for 64x256-ushort tile: 16B chunk ch XOR'd by row&7.
// Self-inverse: reading ATI(r,ch) returns chunk ch of row r.
#define ATI(r, ch) (((r) << 8) + ((((ch) ^ ((r)&7))) << 3))

// ---------------------------------------------------------------- kpack
__global__ __launch_bounds__(256) void kpack(
    const float* __restrict__ aw, const float* __restrict__ qw,
    const float* __restrict__ prw, const float* __restrict__ ow,
    const float* __restrict__ sw1, const float* __restrict__ rpb,
    unsigned short* __restrict__ awp, unsigned short* __restrict__ qwp,
    unsigned short* __restrict__ prwp, unsigned short* __restrict__ owp,
    unsigned short* __restrict__ sw1p, unsigned short* __restrict__ bt) {
  const int b = blockIdx.x;
  if (b >= 356) {  // bias expansion: biasT[h][n][m] f16
    const int i = (b - 356) * 256 + threadIdx.x;  // 32768 total
    const int h = i >> 12, n = (i >> 6) & 63, m = i & 63;
    const int ny = n >> 3, nx = n & 7, my = m >> 3, mx = m & 7;
    const float v = rpb[((ny - my + 7) * 15 + (nx - mx + 7)) * 8 + h];
    bt[i] = __builtin_bit_cast(unsigned short, (_Float16)v);
    return;
  }
  const float* src; unsigned short* dst; int fs, K, N, NT, trans, f16o;
  if (b < 64)       { fs = b;       src = aw;  dst = awp;  K = 256; N = 128; NT = 8;  trans = 0; f16o = 0; }
  else if (b < 160) { fs = b - 64;  src = qw;  dst = qwp;  K = 128; N = 384; NT = 24; trans = 0; f16o = 0; }
  else if (b < 224) { fs = b - 160; src = prw; dst = prwp; K = 256; N = 128; NT = 8;  trans = 1; f16o = 1; }
  else if (b < 352) { fs = b - 224; src = ow;  dst = owp;  K = 256; N = 256; NT = 16; trans = 0; f16o = 0; }
  else              { fs = b - 352; src = sw1; dst = sw1p; K = 128; N = 16;  NT = 1;  trans = 1; f16o = 0; }
  const int ks = fs / NT, nt = fs % NT;
  for (int idx = threadIdx.x; idx < 512; idx += 256) {
    const int l = idx >> 3, i = idx & 7;
    const int k = ks * 32 + ((l >> 4) << 3) + i, n = nt * 16 + (l & 15);
    const float v = trans ? src[n * K + k] : src[k * N + n];
    dst[(fs * 64 + l) * 8 + i] =
        f16o ? __builtin_bit_cast(unsigned short, (_Float16)v) : f2bf(v);
  }
}

// ---------------------------------------------------------------- k1
__global__ __launch_bounds__(256) void k1_attn_ln(
    const float* __restrict__ x, const unsigned short* __restrict__ awp,
    const float* __restrict__ ab, const float* __restrict__ lg,
    const float* __restrict__ lb, unsigned short* __restrict__ xattn,
    unsigned short* __restrict__ xb) {
  const int tid = threadIdx.x, w = tid >> 6, l = tid & 63;
  const int lr = l & 15, lg4 = l >> 4;
  const int r0 = blockIdx.x * 64 + w * 16;
  const float* xp = x + (size_t)(r0 + lr) * 256 + lg4 * 8;
  unsigned short* xbp = xb + (size_t)(r0 + lr) * 256 + lg4 * 8;
  short8 a[8];
#pragma unroll
  for (int ks = 0; ks < 8; ++ks) {
    const float4 f0 = *(const float4*)(xp + ks * 32);
    const float4 f1 = *(const float4*)(xp + ks * 32 + 4);
    short8 av;
    av[0] = f2bf(f0.x); av[1] = f2bf(f0.y); av[2] = f2bf(f0.z); av[3] = f2bf(f0.w);
    av[4] = f2bf(f1.x); av[5] = f2bf(f1.y); av[6] = f2bf(f1.z); av[7] = f2bf(f1.w);
    a[ks] = av;
    uint4 hv;
    hv.x = pkh(f0.x, f0.y); hv.y = pkh(f0.z, f0.w);
    hv.z = pkh(f1.x, f1.y); hv.w = pkh(f1.z, f1.w);
    *(uint4*)(xbp + ks * 32) = hv;
  }
  f32x4 acc[8];
#pragma unroll
  for (int nt = 0; nt < 8; ++nt) acc[nt] = (f32x4)0.f;
#pragma unroll
  for (int nt = 0; nt < 8; ++nt)
#pragma unroll
    for (int ks = 0; ks < 8; ++ks) {
      const short8 bfr = *(const short8*)(awp + ((ks * 8 + nt) * 64 + l) * 8);
      acc[nt] = __builtin_amdgcn_mfma_f32_16x16x32_bf16(a[ks], bfr, acc[nt], 0, 0, 0);
    }
  float bias[8], gam[8], bet[8];
#pragma unroll
  for (int nt = 0; nt < 8; ++nt) {
    const int col = nt * 16 + lr;
    bias[nt] = ab[col]; gam[nt] = lg[col]; bet[nt] = lb[col];
  }
#pragma unroll
  for (int j = 0; j < 4; ++j) {
    float s = 0.f, qq = 0.f;
#pragma unroll
    for (int nt = 0; nt < 8; ++nt) {
      const float v = acc[nt][j] + bias[nt];
      acc[nt][j] = v; s += v; qq += v * v;
    }
    s += __shfl_xor(s, 1); s += __shfl_xor(s, 2);
    s += __shfl_xor(s, 4); s += __shfl_xor(s, 8);
    qq += __shfl_xor(qq, 1); qq += __shfl_xor(qq, 2);
    qq += __shfl_xor(qq, 4); qq += __shfl_xor(qq, 8);
    const float mean = s * (1.f / 128.f);
    const float var = qq * (1.f / 128.f) - mean * mean;
    const float rstd = rsqrtf(var + 1e-5f);
    const int row = r0 + lg4 * 4 + j;
#pragma unroll
    for (int nt = 0; nt < 8; ++nt)
      xattn[(size_t)row * 128 + nt * 16 + lr] =
          f2bf((acc[nt][j] - mean) * rstd * gam[nt] + bet[nt]);
  }
}

// ---------------------------------------------------------------- k25
__global__ __launch_bounds__(256) void k25_conv(
    const unsigned short* __restrict__ xb, const float* __restrict__ cw,
    const float* __restrict__ cb, const float* __restrict__ bg,
    const float* __restrict__ bb, const unsigned short* __restrict__ prwp,
    const float* __restrict__ prb, unsigned short* __restrict__ xpr,
    float* __restrict__ gpart) {
  __shared__ unsigned short gl[32][264];
  const int tid = threadIdx.x;
  const int bid = (blockIdx.x & 7) * 512 + (blockIdx.x >> 3);  // XCD swizzle
  const int b = bid >> 7;
  const int y = (bid >> 1) & 63;
  const int xt = (bid & 1) * 32;
  const int w = tid >> 6, l = tid & 63;
  {
    const int c0 = l << 2;
    h2v w01[9], w23[9];
#pragma unroll
    for (int k = 0; k < 9; ++k) {
      w01[k][0] = (_Float16)cw[(c0 + 0) * 9 + k];
      w01[k][1] = (_Float16)cw[(c0 + 1) * 9 + k];
      w23[k][0] = (_Float16)cw[(c0 + 2) * 9 + k];
      w23[k][1] = (_Float16)cw[(c0 + 3) * 9 + k];
    }
    const float4 cbf = *(const float4*)&cb[c0];
    float4 scf = *(const float4*)&bg[c0];
    scf.x *= BNR; scf.y *= BNR; scf.z *= BNR; scf.w *= BNR;
    const float4 sbf = *(const float4*)&bb[c0];
    h2v cb01 = {(_Float16)cbf.x, (_Float16)cbf.y};
    h2v cb23 = {(_Float16)cbf.z, (_Float16)cbf.w};
    h2v sc01 = {(_Float16)scf.x, (_Float16)scf.y};
    h2v sc23 = {(_Float16)scf.z, (_Float16)scf.w};
    h2v sb01 = {(_Float16)sbf.x, (_Float16)sbf.y};
    h2v sb23 = {(_Float16)sbf.z, (_Float16)sbf.w};
    float4 gsum = make_float4(0.f, 0.f, 0.f, 0.f);
    const int px0 = xt + w * 8;
#pragma unroll
    for (int sc2 = 0; sc2 < 2; ++sc2) {
      const int p0 = px0 + sc2 * 4;
      h2v v0[3][6], v1[3][6];
#pragma unroll
      for (int dy = 0; dy < 3; ++dy) {
        const int yy = y + dy - 1;
        const bool vy = (unsigned)yy < 64u;
        const int ybase = vy ? ((b * 64 + (yy >> 3) * 8) * 64 + (yy & 7) * 8) : 0;
#pragma unroll
        for (int q = 0; q < 6; ++q) {
          const int xx = p0 - 1 + q;
          h2v a = (h2v)(_Float16)0.f, c = (h2v)(_Float16)0.f;
          if (vy && (unsigned)xx < 64u) {
            const int row = ybase + (xx >> 3) * 64 + (xx & 7);
            const uint2 u = *(const uint2*)&xb[(size_t)row * 256 + c0];
            a = __builtin_bit_cast(h2v, u.x);
            c = __builtin_bit_cast(h2v, u.y);
          }
          v0[dy][q] = a; v1[dy][q] = c;
        }
      }
#pragma unroll
      for (int p = 0; p < 4; ++p) {
        h2v s0 = cb01, s1 = cb23;
#pragma unroll
        for (int dy = 0; dy < 3; ++dy)
#pragma unroll
          for (int dx = 0; dx < 3; ++dx) {
            s0 = w01[dy * 3 + dx] * v0[dy][p + dx] + s0;
            s1 = w23[dy * 3 + dx] * v1[dy][p + dx] + s1;
          }
        s0 = s0 * sc01 + sb01;
        s1 = s1 * sc23 + sb23;
        const float g0 = gelu_f((float)s0[0]), g1 = gelu_f((float)s0[1]);
        const float g2 = gelu_f((float)s1[0]), g3 = gelu_f((float)s1[1]);
        uint2 pk;
        pk.x = pkh(g0, g1); pk.y = pkh(g2, g3);
        *(uint2*)&gl[w * 8 + sc2 * 4 + p][c0] = pk;
        gsum.x += g0; gsum.y += g1; gsum.z += g2; gsum.w += g3;
      }
    }
    *(float4*)&gpart[(size_t)bid * 256 + c0] = gsum;
  }
  __syncthreads();
  const int lr = l & 15, lg4 = l >> 4;
  const int mr0 = (w & 1) * 16, nt0 = (w >> 1) * 4;
  half8 a[8];
#pragma unroll
  for (int ks = 0; ks < 8; ++ks)
    a[ks] = __builtin_bit_cast(half8,
                               *(const short8*)&gl[mr0 + lr][ks * 32 + lg4 * 8]);
  f32x4 acc[4];
#pragma unroll
  for (int nt = 0; nt < 4; ++nt) acc[nt] = (f32x4)0.f;
#pragma unroll
  for (int nt = 0; nt < 4; ++nt)
#pragma unroll
    for (int ks = 0; ks < 8; ++ks) {
      const half8 bfr = __builtin_bit_cast(
          half8, *(const short8*)(prwp + ((ks * 8 + nt0 + nt) * 64 + l) * 8));
      acc[nt] = __builtin_amdgcn_mfma_f32_16x16x32_f16(a[ks], bfr, acc[nt], 0, 0, 0);
    }
#pragma unroll
  for (int nt = 0; nt < 4; ++nt) {
    const int col = (nt0 + nt) * 16 + lr;
    const float bv = prb[col];
#pragma unroll
    for (int j = 0; j < 4; ++j) {
      const int pix = (b * 64 + y) * 64 + xt + mr0 + lg4 * 4 + j;
      xpr[(size_t)pix * 128 + col] = f2bf(acc[nt][j] + bv);
    }
  }
}

// ---------------------------------------------------------------- k3
__global__ __launch_bounds__(128) void k3_ci(
    const float* __restrict__ gp, const float* __restrict__ w1,
    const float* __restrict__ b1, const float* __restrict__ g1,
    const float* __restrict__ bb1, const float* __restrict__ w2,
    const float* __restrict__ b2, float* __restrict__ cis) {
  __shared__ float gm[256];
  __shared__ float c1[32];
  const int b = blockIdx.x, tid = threadIdx.x;
  for (int c = tid; c < 256; c += 128) {
    float s = 0.f;
    for (int p = 0; p < 128; ++p) s += gp[(size_t)(b * 128 + p) * 256 + c];
    gm[c] = s * (1.f / 4096.f);
  }
  __syncthreads();
  if (tid < 32) {
    float s = b1[tid];
    for (int c = 0; c < 256; ++c) s = fmaf(gm[c], w1[tid * 256 + c], s);
    s = s * (g1[tid] * BNR) + bb1[tid];
    c1[tid] = gelu_f(s);
  }
  __syncthreads();
  float s = b2[tid];
#pragma unroll
  for (int i = 0; i < 32; ++i) s = fmaf(c1[i], w2[tid * 32 + i], s);
  cis[b * 128 + tid] = 1.f / (1.f + __expf(-s));
}

// ---------------------------------------------------------------- k46
// Fused qkv+attention+tail, bounds(256,4), 2 barriers only.
// LN apply + gating folded into final-GEMM fragment loads (wave-local
// statl/sifl; params staged in LDS); nontemporal out stores.
__global__ __launch_bounds__(256, 4) void k46_attn_tail(
    const unsigned short* __restrict__ xa, const unsigned short* __restrict__ qwp,
    const float* __restrict__ qb, const float* __restrict__ cis,
    const unsigned short* __restrict__ biasT, const unsigned short* __restrict__ xpr,
    const unsigned short* __restrict__ sw1p, const float* __restrict__ sb1,
    const float* __restrict__ sgc, const float* __restrict__ sbc,
    const float* __restrict__ sw2, const float* __restrict__ sb2,
    const float* __restrict__ cg, const float* __restrict__ cbb,
    const float* __restrict__ ag, const float* __restrict__ abb,
    const unsigned short* __restrict__ owp, const float* __restrict__ ob,
    float* __restrict__ out) {
  __shared__ __align__(16) unsigned char Ubuf[35840];  // QS|KS union; At overlay
  __shared__ float sifl[64];
  __shared__ float statl[64][2];
  __shared__ float pl[512];  // [ag | abb | cg*BNR | cbb]
  _Float16(*QS)[64][36] = reinterpret_cast<_Float16(*)[64][36]>(Ubuf);
  _Float16(*KS)[64][34] = reinterpret_cast<_Float16(*)[64][34]>(Ubuf + 18432);
  unsigned short* At = (unsigned short*)Ubuf;  // [64*256] (32KB)
  const int tid = threadIdx.x;
  const int win = blockIdx.x, img = win >> 6;
  const int w = tid >> 6, l = tid & 63, lr = l & 15, lg4 = l >> 4;
  const int wy = (win >> 3) & 7, wx = win & 7;
  // stage LN/gating params (consumed after barrier 2)
  for (int i = tid; i < 512; i += 256) {
    float v;
    if (i < 128) v = ag[i];
    else if (i < 256) v = abb[i - 128];
    else if (i < 384) v = cg[i - 256] * BNR;
    else v = cbb[i - 384];
    pl[i] = v;
  }
  // ---- pass A: Q (nt 2w,2w+1), K (nt 8+2w,8+2w+1) -> LDS transpose
  {
    float qbv[4];
#pragma unroll
    for (int t = 0; t < 4; ++t) {
      const int gnt = (t < 2) ? (2 * w + t) : (8 + 2 * w + t - 2);
      qbv[t] = qb[gnt * 16 + lr];
    }
    f32x4 acc[4][4];
#pragma unroll
    for (int mt = 0; mt < 4; ++mt)
#pragma unroll
      for (int t = 0; t < 4; ++t) acc[mt][t] = (f32x4)0.f;
#pragma unroll
    for (int ks = 0; ks < 4; ++ks) {
      short8 a[4];
#pragma unroll
      for (int mt = 0; mt < 4; ++mt)
        a[mt] = *(const short8*)(xa + (size_t)(win * 64 + mt * 16 + lr) * 128 +
                                 ks * 32 + lg4 * 8);
#pragma unroll
      for (int t = 0; t < 4; ++t) {
        const int gnt = (t < 2) ? (2 * w + t) : (8 + 2 * w + t - 2);
        const short8 bfr = *(const short8*)(qwp + ((ks * 24 + gnt) * 64 + l) * 8);
#pragma unroll
        for (int mt = 0; mt < 4; ++mt)
          acc[mt][t] = __builtin_amdgcn_mfma_f32_16x16x32_bf16(a[mt], bfr,
                                                               acc[mt][t], 0, 0, 0);
      }
    }
#pragma unroll
    for (int mt = 0; mt < 4; ++mt)
#pragma unroll
      for (int t = 0; t < 4; ++t)
#pragma unroll
        for (int j = 0; j < 4; ++j) {
          const int row = mt * 16 + lg4 * 4 + j;
          const float v = acc[mt][t][j] + qbv[t];
          if (t < 2) QS[w][row][t * 16 + lr] = (_Float16)(v * 0.25f);
          else KS[w][row][(t - 2) * 16 + lr] = (_Float16)v;
        }
  }
  // ---- pass B: V (nt 16+2w,16+2w+1) kept in regs as PV B-frags
  half4 bV2[2][4];
  {
    float qbv[2], cisv[2];
#pragma unroll
    for (int t = 0; t < 2; ++t) {
      qbv[t] = qb[(16 + 2 * w + t) * 16 + lr];
      cisv[t] = cis[img * 128 + (2 * w + t) * 16 + lr];
    }
    f32x4 accv[4][2];
#pragma unroll
    for (int mt = 0; mt < 4; ++mt)
#pragma unroll
      for (int t = 0; t < 2; ++t) accv[mt][t] = (f32x4)0.f;
#pragma unroll
    for (int ks = 0; ks < 4; ++ks) {
      short8 a[4];
#pragma unroll
      for (int mt = 0; mt < 4; ++mt)
        a[mt] = *(const short8*)(xa + (size_t)(win * 64 + mt * 16 + lr) * 128 +
                                 ks * 32 + lg4 * 8);
#pragma unroll
      for (int t = 0; t < 2; ++t) {
        const short8 bfr =
            *(const short8*)(qwp + ((ks * 24 + 16 + 2 * w + t) * 64 + l) * 8);
#pragma unroll
        for (int mt = 0; mt < 4; ++mt)
          accv[mt][t] = __builtin_amdgcn_mfma_f32_16x16x32_bf16(a[mt], bfr,
                                                                accv[mt][t], 0, 0, 0);
      }
    }
#pragma unroll
    for (int t = 0; t < 2; ++t)
#pragma unroll
      for (int kt = 0; kt < 4; ++kt) {
        half4 p;
#pragma unroll
        for (int i = 0; i < 4; ++i)
          p[i] = (_Float16)((accv[kt][t][i] + qbv[t]) * cisv[t]);
        bV2[t][kt] = p;
      }
  }
  // ---- attention per head, per-nt COLUMN (low register pressure)
  f32x4 o[2][4];
#pragma unroll
  for (int hi = 0; hi < 2; ++hi) {
    const int h = w * 2 + hi;
    half4 aK[4], bQ[4];
#pragma unroll
    for (int mt = 0; mt < 4; ++mt)
      aK[mt] = *(const half4*)&KS[w][mt * 16 + lr][hi * 16 + lg4 * 4];
#pragma unroll
    for (int nt = 0; nt < 4; ++nt)
      bQ[nt] = *(const half4*)&QS[w][nt * 16 + lr][hi * 16 + lg4 * 4];
#pragma unroll
    for (int nt = 0; nt < 4; ++nt) {
      f32x4 sc[4];
#pragma unroll
      for (int mt = 0; mt < 4; ++mt)
        sc[mt] = __builtin_amdgcn_mfma_f32_16x16x16f16(aK[mt], bQ[nt],
                                                       (f32x4)0.f, 0, 0, 0);
      const int n = nt * 16 + lr;
      const unsigned short* bp = biasT + (((h << 6) + n) << 6);
#pragma unroll
      for (int mt = 0; mt < 4; ++mt) {
        const half4 b4 = *(const half4*)(bp + mt * 16 + lg4 * 4);
        sc[mt][0] += (float)b4[0];
        sc[mt][1] += (float)b4[1];
        sc[mt][2] += (float)b4[2];
        sc[mt][3] += (float)b4[3];
      }
      float m0 = -1e30f;
#pragma unroll
      for (int mt = 0; mt < 4; ++mt)
#pragma unroll
        for (int r = 0; r < 4; ++r) m0 = fmaxf(m0, sc[mt][r]);
      m0 = fmaxf(m0, __shfl_xor(m0, 16));
      m0 = fmaxf(m0, __shfl_xor(m0, 32));
      float d0 = 0.f;
#pragma unroll
      for (int mt = 0; mt < 4; ++mt)
#pragma unroll
        for (int r = 0; r < 4; ++r) {
          const float e = __expf(sc[mt][r] - m0);
          sc[mt][r] = e;
          d0 += e;
        }
      d0 += __shfl_xor(d0, 16);
      d0 += __shfl_xor(d0, 32);
      const float inv = 1.f / d0;
      half4 pc[4];
#pragma unroll
      for (int kt = 0; kt < 4; ++kt) {
        half4 p;
#pragma unroll
        for (int r = 0; r < 4; ++r) p[r] = (_Float16)(sc[kt][r] * inv);
        pc[kt] = p;
      }
      o[hi][nt] = (f32x4)0.f;
#pragma unroll
      for (int kt = 0; kt < 4; ++kt)
        o[hi][nt] = __builtin_amdgcn_mfma_f32_16x16x16f16(pc[kt], bV2[hi][kt],
                                                          o[hi][nt], 0, 0, 0);
    }
  }
  // xpr prefetch (latency hides under the coming barrier wait)
  uint4 xr[4];
#pragma unroll
  for (int kk = 0; kk < 4; ++kk) {
    const int i = tid + kk * 256;
    const int r = i >> 4, c16 = i & 15;
    const int pix = (img * 64 + wy * 8 + (r >> 3)) * 64 + wx * 8 + (r & 7);
    xr[kk] = *(const uint4*)&xpr[(size_t)pix * 128 + c16 * 8];
  }
  __syncthreads();  // barrier 1: all waves done reading QS/KS -> At overlay
  // ---- write O (bf16) into At attn half; xpr regs into conv half
#pragma unroll
  for (int hi = 0; hi < 2; ++hi) {
    const int ch = w * 4 + hi * 2 + (lr >> 3), co = lr & 7;
#pragma unroll
    for (int nt = 0; nt < 4; ++nt)
#pragma unroll
      for (int r = 0; r < 4; ++r) {
        const int token = nt * 16 + lg4 * 4 + r;
        At[ATI(token, ch) + co] = f2bf(o[hi][nt][r]);
      }
  }
#pragma unroll
  for (int kk = 0; kk < 4; ++kk) {
    const int i = tid + kk * 256;
    const int r = i >> 4, c16 = i & 15;
    *(uint4*)&At[ATI(r, 16 + c16)] = xr[kk];
  }
  __syncthreads();  // barrier 2: At fully populated; all that follows is
                    // wave-local w.r.t. statl/sifl (rows w*16..w*16+15)
  // ---- LN stats over attn half (rows of own wave band)
  {
    const int r = tid >> 2, q = tid & 3;
    float xv[32];
#pragma unroll
    for (int b8 = 0; b8 < 4; ++b8) ld8(&At[ATI(r, q * 4 + b8)], xv + b8 * 8);
    float ps = 0.f, pq = 0.f;
#pragma unroll
    for (int j = 0; j < 32; ++j) { ps += xv[j]; pq += xv[j] * xv[j]; }
    ps += __shfl_xor(ps, 1); ps += __shfl_xor(ps, 2);
    pq += __shfl_xor(pq, 1); pq += __shfl_xor(pq, 2);
    if (q == 0) {
      const float mean = ps * (1.f / 128.f);
      const float var = pq * (1.f / 128.f) - mean * mean;
      statl[r][0] = mean;
      statl[r][1] = rsqrtf(var + 1e-5f);
    }
  }
  // ---- si MLP via MFMA on raw attn half (own wave band)
  {
    const int row = w * 16 + lr;
    f32x4 sa = (f32x4)0.f;
#pragma unroll
    for (int ks = 0; ks < 4; ++ks) {
      const short8 a4 = *(const short8*)&At[ATI(row, ks * 4 + lg4)];
      const short8 bfr = *(const short8*)(sw1p + (ks * 64 + l) * 8);
      sa = __builtin_amdgcn_mfma_f32_16x16x32_bf16(a4, bfr, sa, 0, 0, 0);
    }
    const float sb1v = sb1[lr], g1v = sgc[lr] * BNR, b1v = sbc[lr];
    const float w2v = sw2[lr], sb2v = sb2[0];
#pragma unroll
    for (int j = 0; j < 4; ++j) {
      float s = (sa[j] + sb1v) * g1v + b1v;
      float p = gelu_f(s) * w2v;
      p += __shfl_xor(p, 1); p += __shfl_xor(p, 2);
      p += __shfl_xor(p, 4); p += __shfl_xor(p, 8);
      if (lr == 0) sifl[w * 16 + lg4 * 4 + j] = p + sb2v;
    }
  }
  // NO barrier: statl/sifl entries read below belong to this wave's band.
  // ---- final GEMM with in-register LN apply (attn) + gating (conv)
  const int row = w * 16 + lr;
  const float mean = statl[row][0], rstd = statl[row][1];
  const float sif = sifl[row];
  short8 af[8];
#pragma unroll
  for (int ks = 0; ks < 8; ++ks) {
    const short8 raw = *(const short8*)&At[ATI(row, ks * 4 + lg4)];
    const int cbase = (ks * 4 + lg4) * 8;  // global col of element 0
    short8 av;
    if (ks < 4) {
#pragma unroll
      for (int i = 0; i < 8; ++i) {
        const float v = bf2f((unsigned short)raw[i]);
        av[i] = f2bf((v - mean) * rstd * pl[cbase + i] + pl[128 + cbase + i]);
      }
    } else {
      const int cc = cbase - 128;
#pragma unroll
      for (int i = 0; i < 8; ++i) {
        const float v = bf2f((unsigned short)raw[i]);
        const float g = 1.f / (1.f + __expf(-sif * v));
        av[i] = f2bf(g * pl[256 + cc + i] + pl[384 + cc + i]);
      }
    }
    af[ks] = av;
  }
  f32x4 acc[16];
#pragma unroll
  for (int nt = 0; nt < 16; ++nt) acc[nt] = (f32x4)0.f;
#pragma unroll
  for (int nt = 0; nt < 16; ++nt)
#pragma unroll
    for (int ks = 0; ks < 8; ++ks) {
      const short8 bfr = *(const short8*)(owp + ((ks * 16 + nt) * 64 + l) * 8);
      acc[nt] = __builtin_amdgcn_mfma_f32_16x16x32_bf16(af[ks], bfr, acc[nt], 0, 0, 0);
    }
#pragma unroll
  for (int nt = 0; nt < 16; ++nt) {
    const int col = nt * 16 + lr;
    const float bv = ob[col];
#pragma unroll
    for (int j = 0; j < 4; ++j)
      __builtin_nontemporal_store(
          acc[nt][j] + bv,
          &out[(size_t)(win * 64 + w * 16 + lg4 * 4 + j) * 256 + col]);
  }
}

// ---------------------------------------------------------------- launch
extern "C" void kernel_launch(void* const* d_in, const int* in_sizes, int n_in,
                              void* d_out, int out_size, void* d_ws,
                              size_t ws_size, hipStream_t stream) {
  (void)in_sizes; (void)n_in; (void)out_size; (void)ws_size;
  const float* x      = (const float*)d_in[0];
  const float* rpb    = (const float*)d_in[1];
  const float* attn_w = (const float*)d_in[2];
  const float* attn_b = (const float*)d_in[3];
  const float* aln_g  = (const float*)d_in[4];
  const float* aln_b  = (const float*)d_in[5];
  const float* conv_w = (const float*)d_in[6];
  const float* conv_b = (const float*)d_in[7];
  const float* cbn_g  = (const float*)d_in[8];
  const float* cbn_b  = (const float*)d_in[9];
  const float* ci_w1  = (const float*)d_in[10];
  const float* ci_b1  = (const float*)d_in[11];
  const float* ci_bg  = (const float*)d_in[12];
  const float* ci_bb  = (const float*)d_in[13];
  const float* ci_w2  = (const float*)d_in[14];
  const float* ci_b2  = (const float*)d_in[15];
  const float* pr_w   = (const float*)d_in[16];
  const float* pr_b   = (const float*)d_in[17];
  const float* cn_g   = (const float*)d_in[18];
  const float* cn_b   = (const float*)d_in[19];
  const float* qkv_w  = (const float*)d_in[20];
  const float* qkv_b  = (const float*)d_in[21];
  const float* si_w1  = (const float*)d_in[22];
  const float* si_b1  = (const float*)d_in[23];
  const float* si_bg  = (const float*)d_in[24];
  const float* si_bb  = (const float*)d_in[25];
  const float* si_w2  = (const float*)d_in[26];
  const float* si_b2  = (const float*)d_in[27];
  const float* an_g   = (const float*)d_in[28];
  const float* an_b   = (const float*)d_in[29];
  const float* out_w  = (const float*)d_in[30];
  const float* out_b  = (const float*)d_in[31];

  unsigned short* xb    = (unsigned short*)d_ws;          // 33,554,432 e (f16)
  unsigned short* xattn = xb + 33554432;                  // 16,777,216 e
  unsigned short* xpr   = xattn + 16777216;               // 16,777,216 e
  float* gpart = (float*)(xpr + 16777216);                // 1,048,576 f
  float* cis   = gpart + 1048576;                         // 4,096 f
  unsigned short* awp   = (unsigned short*)(cis + 4096);  // 32,768 e
  unsigned short* qwp   = awp + 32768;                    // 49,152 e
  unsigned short* prwp  = qwp + 49152;                    // 32,768 e (f16)
  unsigned short* owp   = prwp + 32768;                   // 65,536 e
  unsigned short* sw1p  = owp + 65536;                    // 2,048 e
  unsigned short* biasT = sw1p + 2048;                    // 32,768 e (f16)

  kpack<<<484, 256, 0, stream>>>(attn_w, qkv_w, pr_w, out_w, si_w1, rpb,
                                 awp, qwp, prwp, owp, sw1p, biasT);
  k1_attn_ln<<<2048, 256, 0, stream>>>(x, awp, attn_b, aln_g, aln_b, xattn, xb);
  k25_conv<<<4096, 256, 0, stream>>>(xb, conv_w, conv_b, cbn_g, cbn_b, prwp,
                                     pr_b, xpr, gpart);
  k3_ci<<<32, 128, 0, stream>>>(gpart, ci_w1, ci_b1, ci_bg, ci_bb, ci_w2,
                                ci_b2, cis);
  k46_attn_tail<<<2048, 256, 0, stream>>>(
      xattn, qwp, qkv_b, cis, biasT, xpr, sw1p, si_b1, si_bg, si_bb, si_w2,
      si_b2, cn_g, cn_b, an_g, an_b, owp, out_b, (float*)d_out);
}